// Round 1
// baseline (74.281 us; speedup 1.0000x reference)
//
#include <hip/hip_runtime.h>
#include <hip/hip_bf16.h>

// 4-qubit QNN: encoding RY(x) per sample + fixed variational block (shared
// weights) + <Z_q> readout.  The variational block is a constant 16x16
// unitary U; <Z_q> = s0^T Re(U^+ Z_q U) s0 with s0 a product state in
// v(t)=[cos(t/2),sin(t/2)].  This collapses each output to a 5x5 bilinear
// form in the degree-4 monomials of (c0,s0) and (c1,s1):
//   out_q = sum_{m,n} C[q][m][n] * c0^{4-m} s0^m * c1^{4-n} s1^n
// Setup kernel (1 block) builds U from the 36 weights and reduces to
// C[4][5][5] = 100 floats in d_ws; batch kernel is then pure streaming.
//
// v2 (this round): batch kernel packs TWO samples per lane (float4 x-loads,
// float2 arithmetic -> v_pk_fma_f32-shaped code), and grid doubled to 1024
// blocks (4 samples/thread) for latency hiding.  Math unchanged.

__global__ __launch_bounds__(256) void qnn_setup(const float* __restrict__ w,
                                                 float* __restrict__ C_out) {
    __shared__ float Ur[16][16];
    __shared__ float Ui[16][16];
    __shared__ float Csh[100];
    const int t = threadIdx.x;

    if (t < 100) Csh[t] = 0.0f;

    if (t < 16) {
        // Thread t owns column t of U (a state vector); left-multiplying U by
        // a gate applies the gate independently to each column.
        float ar[16], ai[16];
#pragma unroll
        for (int i = 0; i < 16; i++) { ar[i] = (i == t) ? 1.0f : 0.0f; ai[i] = 0.0f; }

#pragma unroll
        for (int l = 0; l < 3; l++) {
#pragma unroll
            for (int wq = 0; wq < 4; wq++) {
                const int st = 1 << (3 - wq);   // wire wq lives at bit (3-wq)
                float th, s, c;
                // RX(w[l][wq][0]):  a' = c*a - i s*b ; b' = -i s*a + c*b
                th = w[(l * 4 + wq) * 3 + 0] * 0.5f;
                __sincosf(th, &s, &c);
#pragma unroll
                for (int lo = 0; lo < 16; lo++) if (!(lo & st)) {
                    const int hi = lo | st;
                    const float arl = ar[lo], ail = ai[lo], arh = ar[hi], aih = ai[hi];
                    ar[lo] = c * arl + s * aih;
                    ai[lo] = c * ail - s * arh;
                    ar[hi] = c * arh + s * ail;
                    ai[hi] = c * aih - s * arl;
                }
                // RY(w[l][wq][1]):  a' = c*a - s*b ; b' = s*a + c*b (real)
                th = w[(l * 4 + wq) * 3 + 1] * 0.5f;
                __sincosf(th, &s, &c);
#pragma unroll
                for (int lo = 0; lo < 16; lo++) if (!(lo & st)) {
                    const int hi = lo | st;
                    const float arl = ar[lo], ail = ai[lo], arh = ar[hi], aih = ai[hi];
                    ar[lo] = c * arl - s * arh;
                    ai[lo] = c * ail - s * aih;
                    ar[hi] = s * arl + c * arh;
                    ai[hi] = s * ail + c * aih;
                }
                // RZ(w[l][wq][2]):  a' = (c - i s)*a ; b' = (c + i s)*b
                th = w[(l * 4 + wq) * 3 + 2] * 0.5f;
                __sincosf(th, &s, &c);
#pragma unroll
                for (int lo = 0; lo < 16; lo++) if (!(lo & st)) {
                    const int hi = lo | st;
                    const float arl = ar[lo], ail = ai[lo], arh = ar[hi], aih = ai[hi];
                    ar[lo] = c * arl + s * ail;
                    ai[lo] = c * ail - s * arl;
                    ar[hi] = c * arh - s * aih;
                    ai[hi] = c * aih + s * arh;
                }
            }
            // CNOT(i, (i+1)%4), i = 0..3, applied sequentially
#pragma unroll
            for (int ci = 0; ci < 4; ci++) {
                const int cst = 1 << (3 - ci);
                const int tst = 1 << (3 - ((ci + 1) & 3));
#pragma unroll
                for (int k = 0; k < 16; k++) if ((k & cst) && !(k & tst)) {
                    const int k2 = k | tst;
                    const float tr = ar[k], ti = ai[k];
                    ar[k] = ar[k2]; ai[k] = ai[k2];
                    ar[k2] = tr;    ai[k2] = ti;
                }
            }
        }
#pragma unroll
        for (int i = 0; i < 16; i++) { Ur[i][t] = ar[i]; Ui[i][t] = ai[i]; }
    }
    __syncthreads();

    // Thread t = i*16+j computes M_q[i][j] = Re(sum_k conj(U[k][i]) z_q(k) U[k][j])
    // and folds it into C[q][m][n] where m = popcount of x0-wire bits of (i,j),
    // n = popcount of x1-wire bits.  Wires 0,2 (bits 3,1) carry x0; wires 1,3
    // (bits 2,0) carry x1.
    {
        const int i = t >> 4;
        const int j = t & 15;
        float m0 = 0.f, m1 = 0.f, m2 = 0.f, m3 = 0.f;
#pragma unroll
        for (int k = 0; k < 16; k++) {
            const float r = Ur[k][i] * Ur[k][j] + Ui[k][i] * Ui[k][j];
            m0 += ((k >> 3) & 1) ? -r : r;
            m1 += ((k >> 2) & 1) ? -r : r;
            m2 += ((k >> 1) & 1) ? -r : r;
            m3 += ((k >> 0) & 1) ? -r : r;
        }
        const int mm = ((i >> 3) & 1) + ((i >> 1) & 1) + ((j >> 3) & 1) + ((j >> 1) & 1);
        const int nn = ((i >> 2) & 1) + (i & 1) + ((j >> 2) & 1) + (j & 1);
        atomicAdd(&Csh[0 * 25 + mm * 5 + nn], m0);
        atomicAdd(&Csh[1 * 25 + mm * 5 + nn], m1);
        atomicAdd(&Csh[2 * 25 + mm * 5 + nn], m2);
        atomicAdd(&Csh[3 * 25 + mm * 5 + nn], m3);
    }
    __syncthreads();
    if (t < 100) C_out[t] = Csh[t];
}

// ---------------------------------------------------------------------------
// Batch kernel v2: two samples packed per lane (x/y of float2 math).

__device__ __forceinline__ float2 mul2(float2 a, float2 b) {
    return make_float2(a.x * b.x, a.y * b.y);
}
__device__ __forceinline__ float2 fma2(float s, float2 a, float2 b) {
    // scalar (wave-uniform) coefficient broadcast into both halves
    return make_float2(fmaf(s, a.x, b.x), fmaf(s, a.y, b.y));
}
__device__ __forceinline__ float2 fma22(float2 s, float2 a, float2 b) {
    return make_float2(fmaf(s.x, a.x, b.x), fmaf(s.y, a.y, b.y));
}

constexpr int PAIRS = 2;   // sample-pairs per thread => 4 samples/thread

__global__ __launch_bounds__(256) void qnn_batch(const float4* __restrict__ x,
                                                 const float* __restrict__ C,
                                                 float4* __restrict__ out,
                                                 int npairs, int B) {
    // Wave-uniform coefficient load (uniform pointer + constant offsets ->
    // scalar-load promotion expected).
    float cf[100];
#pragma unroll
    for (int i = 0; i < 100; i++) cf[i] = C[i];

    const int base = blockIdx.x * (256 * PAIRS) + threadIdx.x;
#pragma unroll
    for (int k = 0; k < PAIRS; k++) {
        const int p = base + k * 256;
        if (p < npairs) {
            // sample A = (xv.x, xv.y), sample B = (xv.z, xv.w)
            const float4 xv = x[p];
            float2 s0, c0, s1, c1;
            __sincosf(xv.x * 0.5f, &s0.x, &c0.x);
            __sincosf(xv.z * 0.5f, &s0.y, &c0.y);
            __sincosf(xv.y * 0.5f, &s1.x, &c1.x);
            __sincosf(xv.w * 0.5f, &s1.y, &c1.y);

            const float2 cc0 = mul2(c0, c0), ss0 = mul2(s0, s0), cs0 = mul2(c0, s0);
            const float2 cc1 = mul2(c1, c1), ss1 = mul2(s1, s1), cs1 = mul2(c1, s1);
            float2 p0[5] = { mul2(cc0, cc0), mul2(cc0, cs0), mul2(cs0, cs0),
                             mul2(cs0, ss0), mul2(ss0, ss0) };
            float2 p1[5] = { mul2(cc1, cc1), mul2(cc1, cs1), mul2(cs1, cs1),
                             mul2(cs1, ss1), mul2(ss1, ss1) };
            float2 o[4];
#pragma unroll
            for (int q = 0; q < 4; q++) {
                float2 acc = make_float2(0.0f, 0.0f);
#pragma unroll
                for (int m = 0; m < 5; m++) {
                    float2 inner = make_float2(0.0f, 0.0f);
#pragma unroll
                    for (int n = 0; n < 5; n++)
                        inner = fma2(cf[q * 25 + m * 5 + n], p1[n], inner);
                    acc = fma22(p0[m], inner, acc);
                }
                o[q] = acc;
            }
            out[2 * p]     = make_float4(o[0].x, o[1].x, o[2].x, o[3].x);
            out[2 * p + 1] = make_float4(o[0].y, o[1].y, o[2].y, o[3].y);
        }
    }

    // Odd-B tail (never taken for B = 1M; kept for generality).
    if ((B & 1) && blockIdx.x == 0 && threadIdx.x == 0) {
        const int b = B - 1;
        const float2 xt = ((const float2*)x)[b];
        float st0, ct0, st1, ct1;
        __sincosf(xt.x * 0.5f, &st0, &ct0);
        __sincosf(xt.y * 0.5f, &st1, &ct1);
        const float cc0 = ct0 * ct0, ss0 = st0 * st0, cs0 = ct0 * st0;
        const float cc1 = ct1 * ct1, ss1 = st1 * st1, cs1 = ct1 * st1;
        float q0[5] = { cc0 * cc0, cc0 * cs0, cs0 * cs0, cs0 * ss0, ss0 * ss0 };
        float q1[5] = { cc1 * cc1, cc1 * cs1, cs1 * cs1, cs1 * ss1, ss1 * ss1 };
        float o[4];
#pragma unroll
        for (int q = 0; q < 4; q++) {
            float acc = 0.0f;
#pragma unroll
            for (int m = 0; m < 5; m++) {
                float inner = 0.0f;
#pragma unroll
                for (int n = 0; n < 5; n++)
                    inner = fmaf(cf[q * 25 + m * 5 + n], q1[n], inner);
                acc = fmaf(q0[m], inner, acc);
            }
            o[q] = acc;
        }
        out[b] = make_float4(o[0], o[1], o[2], o[3]);
    }
}

extern "C" void kernel_launch(void* const* d_in, const int* in_sizes, int n_in,
                              void* d_out, int out_size, void* d_ws, size_t ws_size,
                              hipStream_t stream) {
    const float* x = (const float*)d_in[0];      // (B, 2) float32
    const float* w = (const float*)d_in[1];      // (3, 4, 3) float32
    float* C = (float*)d_ws;                     // 100 floats scratch
    const int B = in_sizes[0] / 2;

    qnn_setup<<<1, 256, 0, stream>>>(w, C);

    const int npairs = B >> 1;                   // two samples per float4 load
    int grid = (npairs + 256 * PAIRS - 1) / (256 * PAIRS);
    if (grid < 1) grid = 1;
    qnn_batch<<<grid, 256, 0, stream>>>((const float4*)x, C, (float4*)d_out,
                                        npairs, B);
}